// Round 6
// baseline (398.440 us; speedup 1.0000x reference)
//
// VQ layer (gumbel-softmax VQ) fused pipeline for MI355X (gfx950). Round 6.
//
//   K0a split_w : W_h, W_logits (512x512 f32) -> f16 hi/lo planes in ws
//   K0b split_x : X (65536x512 f32) -> f16 hi/lo planes in ws (134 MB)
//   K1  gemm4<0,0>: hiddens = relu(X @ Wh^T + bh) -> f16 hi/lo planes in the
//                   codes half of d_out (free until K3)
//   K2  gemm4<0,1>: logits = hiddens @ Wl^T + bl -> d_out (f32); epilogue
//                   ALSO computes fused gumbel+argmax partials per (row, bn)
//                   -> ws partials (no logits/u re-read in K3)
//   K3b reduce+gather: bi = argmax over 4 partials; codes[row,:] = cb[bi,:]
//
// f32-GEMM emulation: a = hi + lo*2^-12 (f16 split, lo scaled by 2^12), using
// 3 MFMAs: hi.hi -> acc_hh ; hi.lo + lo.hi -> acc_mx ; D = acc_hh + acc_mx*2^-12.
//
// GEMM v4 (round-5 proven presplit path): 128x128 tile, 4 waves (64x64
// out/wave, 4x4 of 16x16x32 f16 MFMA — conflict-free b128 shape), BK=32,
// double-buffered LDS (2 x 32KB, 2 blocks/CU), counted s_waitcnt vmcnt(8) +
// raw s_barrier (prefetch stays in flight across barriers), XOR-swizzled
// global_load_lds source (rule 21), XCD-chunked block swizzle (2048%8==0).
// Round-5 lesson: on-the-fly f32 split (AF32=1) puts ~256 dependent VALU
// cycles between ds_read and MFMA -> 190us vs 55us presplit. Presplit wins.

#include <hip/hip_runtime.h>
#include <hip/hip_fp16.h>

typedef _Float16 h16;
typedef __attribute__((ext_vector_type(8))) _Float16 h16x8;
typedef __attribute__((ext_vector_type(4))) _Float16 h16x4;
typedef __attribute__((ext_vector_type(4))) float f32x4;

#define KDIM 512
#define NDIM 512
#define LO_SCALE 4096.0f
#define LO_INV   0.000244140625f

__device__ __forceinline__ void gload16(const void* g, void* l) {
  __builtin_amdgcn_global_load_lds((const __attribute__((address_space(1))) void*)g,
                                   (__attribute__((address_space(3))) void*)l, 16, 0, 0);
}

#define WAITV(n) asm volatile("s_waitcnt vmcnt(" #n ")" ::: "memory")
#define WAITL0() asm volatile("s_waitcnt lgkmcnt(0)" ::: "memory")

// ---------------- K0a: split weights into f16 hi/lo planes ----------------
__global__ void split_w(const float* __restrict__ Wh, const float* __restrict__ Wl,
                        h16* __restrict__ WhHi, h16* __restrict__ WhLo,
                        h16* __restrict__ WlHi, h16* __restrict__ WlLo) {
  int i = blockIdx.x * 256 + threadIdx.x;          // 262144 elements
  float a = Wh[i];
  h16 h = (h16)a;
  WhHi[i] = h; WhLo[i] = (h16)((a - (float)h) * LO_SCALE);
  a = Wl[i];
  h = (h16)a;
  WlHi[i] = h; WlLo[i] = (h16)((a - (float)h) * LO_SCALE);
}

// ---------------- K0b: split inputs into f16 hi/lo planes ----------------
__global__ void split_x(const f32x4* __restrict__ X, h16x4* __restrict__ XHi,
                        h16x4* __restrict__ XLo) {
  int i = blockIdx.x * 256 + threadIdx.x;          // 8388608 f32x4 groups
  f32x4 a = X[i];
  h16x4 hv, lv;
#pragma unroll
  for (int j = 0; j < 4; ++j) {
    h16 h = (h16)a[j];
    hv[j] = h;
    lv[j] = (h16)((a[j] - (float)h) * LO_SCALE);
  }
  XHi[i] = hv; XLo[i] = lv;
}

// ====== GEMM v4: C[m,n] = sum_k A[m,k]*B[n,k] (+bias, epilogue) ======
// AF32=1: A is f32, staged raw and split in-register (slow; fallback only).
// AF32=0: A is presplit f16 hi/lo planes.
// EPI 0: relu + split -> OHi/OLo planes.
// EPI 1: f32 -> Cf32, plus fused gumbel+argmax partials -> part[row*4+bn].
// Both epilogues repack through LDS for fully-coalesced 16B/lane stores.
template <int AF32, int EPI>
__launch_bounds__(256, 2)
__global__ void gemm4_k(const void* __restrict__ Aptr, const void* __restrict__ AptrLo,
                        const h16* __restrict__ BHi, const h16* __restrict__ BLo,
                        const float* __restrict__ bias,
                        float* __restrict__ Cf32,
                        h16* __restrict__ OHi, h16* __restrict__ OLo,
                        const float* __restrict__ U, const int* __restrict__ testing,
                        uint2* __restrict__ part) {
  // LDS: 2 stage buffers x 32KB. Per buffer:
  //   A region [0,16K):  AF32 ? [128 rows][128B f32] : [128 rows][hi64|lo64]
  //   B region [16K,32K): [128 rows][hi64|lo64]
  // 128-B rows, granule-XOR swizzle ^((row&7)<<4) applied on SOURCE (stage)
  // and on ds_read address (involution). Epilogue reuses all 64 KB.
  __shared__ __align__(16) char lds[65536];
  const int tid = threadIdx.x;
  const int wave = tid >> 6, lane = tid & 63;
  // XCD-chunked swizzle: 2048 wgs, 8 XCDs, 256 per XCD (bijective)
  const int wg = (blockIdx.x & 7) * 256 + (blockIdx.x >> 3);
  const int bm = wg >> 2, bn = wg & 3;             // 512 row-tiles x 4 col-tiles
  const int wm = wave >> 1, wn = wave & 1;         // 2x2 wave grid, 64x64/wave
  const long arow0 = (long)bm * 128;
  const int brow0 = bn * 128;
  const int q = lane >> 4, rlo = lane & 15;

  f32x4 acc_hh[4][4] = {};
  f32x4 acc_mx[4][4] = {};

  // Stage K-step kt into buffer at bufoff. LDS dest linear (wave-uniform
  // base; HW adds lane*16); source address carries the lane offset + XOR
  // granule swizzle + plane select. 8 gload16 per lane per stage.
#define STAGE4(bufoff, kt)                                                    \
  {                                                                           \
    _Pragma("unroll")                                                         \
    for (int pass = 0; pass < 4; ++pass) {         /* A region: 16KB */       \
      int p = pass * 4096 + wave * 1024 + lane * 16;                          \
      int row = p >> 7;                                                       \
      int gs = ((p >> 4) & 7) ^ (row & 7);                                    \
      if (AF32) {                                                             \
        long off = (arow0 + row) * 2048 + (kt) * 128 + gs * 16;               \
        gload16((const char*)Aptr + off,                                      \
                lds + (bufoff) + pass * 4096 + wave * 1024);                  \
      } else {                                                                \
        const char* sp = (gs & 4) ? (const char*)AptrLo : (const char*)Aptr;  \
        long off = (arow0 + row) * 1024 + (kt) * 64 + (gs & 3) * 16;          \
        gload16(sp + off, lds + (bufoff) + pass * 4096 + wave * 1024);        \
      }                                                                       \
    }                                                                         \
    _Pragma("unroll")                                                         \
    for (int pass = 0; pass < 4; ++pass) {         /* B region: 16KB */       \
      int p = pass * 4096 + wave * 1024 + lane * 16;                          \
      int row = p >> 7;                                                       \
      int gs = ((p >> 4) & 7) ^ (row & 7);                                    \
      const char* sp = (gs & 4) ? (const char*)BLo : (const char*)BHi;        \
      long off = (long)(brow0 + row) * 1024 + (kt) * 64 + (gs & 3) * 16;      \
      gload16(sp + off, lds + (bufoff) + 16384 + pass * 4096 + wave * 1024);  \
    }                                                                         \
  }

  STAGE4(0, 0);
  STAGE4(32768, 1);

#pragma unroll
  for (int t = 0; t < 16; ++t) {
    // counted wait: stage-t loads (oldest 8) landed; stage-(t+1) in flight
    if (t < 15) { WAITV(8); } else { WAITV(0); }
    __builtin_amdgcn_sched_barrier(0);
    __builtin_amdgcn_s_barrier();                  // all waves' t-loads landed
    __builtin_amdgcn_sched_barrier(0);

    const char* buf = lds + (t & 1) * 32768;
    h16x8 ah[4], al[4], bh[4], bl[4];
#pragma unroll
    for (int i = 0; i < 4; ++i) {
      int row = wm * 64 + i * 16 + rlo;
      int sw = (row & 7) << 4;
      if (AF32) {
        f32x4 u0 = *(const f32x4*)(buf + row * 128 + ((q * 32) ^ sw));
        f32x4 u1 = *(const f32x4*)(buf + row * 128 + ((q * 32 + 16) ^ sw));
#pragma unroll
        for (int e = 0; e < 4; ++e) {
          h16 h = (h16)u0[e];
          ah[i][e] = h; al[i][e] = (h16)((u0[e] - (float)h) * LO_SCALE);
          h16 h2 = (h16)u1[e];
          ah[i][4 + e] = h2; al[i][4 + e] = (h16)((u1[e] - (float)h2) * LO_SCALE);
        }
      } else {
        ah[i] = *(const h16x8*)(buf + row * 128 + ((q * 16) ^ sw));
        al[i] = *(const h16x8*)(buf + row * 128 + ((q * 16 + 64) ^ sw));
      }
      int rb = wn * 64 + i * 16 + rlo;
      int swb = (rb & 7) << 4;
      bh[i] = *(const h16x8*)(buf + 16384 + rb * 128 + ((q * 16) ^ swb));
      bl[i] = *(const h16x8*)(buf + 16384 + rb * 128 + ((q * 16 + 64) ^ swb));
    }
#pragma unroll
    for (int i = 0; i < 4; ++i)
#pragma unroll
      for (int j = 0; j < 4; ++j)
        acc_hh[i][j] = __builtin_amdgcn_mfma_f32_16x16x32_f16(ah[i], bh[j], acc_hh[i][j], 0, 0, 0);
#pragma unroll
    for (int i = 0; i < 4; ++i)
#pragma unroll
      for (int j = 0; j < 4; ++j)
        acc_mx[i][j] = __builtin_amdgcn_mfma_f32_16x16x32_f16(ah[i], bl[j], acc_mx[i][j], 0, 0, 0);
#pragma unroll
    for (int i = 0; i < 4; ++i)
#pragma unroll
      for (int j = 0; j < 4; ++j)
        acc_mx[i][j] = __builtin_amdgcn_mfma_f32_16x16x32_f16(al[i], bh[j], acc_mx[i][j], 0, 0, 0);

    WAITL0();                                      // our reads of buf done
    __builtin_amdgcn_sched_barrier(0);
    __builtin_amdgcn_s_barrier();                  // safe to overwrite buf
    __builtin_amdgcn_sched_barrier(0);
    if (t + 2 < 16) STAGE4((t & 1) * 32768, t + 2);
  }
#undef STAGE4

  // ---- epilogue. C/D layout (16x16, m89): col=lane&15, row=(lane>>4)*4+r.
  // Repack tile through LDS (stage buffers dead), then coalesced stores.
#pragma unroll
  for (int j = 0; j < 4; ++j) {
    int lcol = wn * 64 + j * 16 + rlo;
    float bv = bias[bn * 128 + lcol];
#pragma unroll
    for (int i = 0; i < 4; ++i)
#pragma unroll
      for (int r = 0; r < 4; ++r) {
        int lrow = wm * 64 + i * 16 + q * 4 + r;
        float v = acc_hh[i][j][r] + acc_mx[i][j][r] * LO_INV + bv;
        if (EPI == 0) {
          v = fmaxf(v, 0.0f);
          h16 h = (h16)v;
          h16 l = (h16)((v - (float)h) * LO_SCALE);
          unsigned uu = (unsigned)__builtin_bit_cast(unsigned short, h) |
                        ((unsigned)__builtin_bit_cast(unsigned short, l) << 16);
          *(unsigned*)(lds + lrow * 512 + lcol * 4) = uu;
        } else {
          *(float*)(lds + lrow * 512 + lcol * 4) = v;
        }
      }
  }
  __syncthreads();
  const int test = (EPI == 1) ? *testing : 0;
#pragma unroll
  for (int pass = 0; pass < 16; ++pass) {
    int o = pass * 4096 + tid * 16;
    int lrow = o >> 9;                             // 512-B packed rows
    int lcb = o & 511;
    if (EPI == 0) {
      uint4 d = *(const uint4*)(lds + o);
      uint2 hi, lo;
      hi.x = (d.x & 0xffffu) | (d.y << 16);
      hi.y = (d.z & 0xffffu) | (d.w << 16);
      lo.x = (d.x >> 16) | (d.y & 0xffff0000u);
      lo.y = (d.z >> 16) | (d.w & 0xffff0000u);
      long gb = (arow0 + lrow) * 1024 + bn * 256 + (lcb >> 1);
      *(uint2*)((char*)OHi + gb) = hi;
      *(uint2*)((char*)OLo + gb) = lo;
    } else {
      f32x4 d = *(const f32x4*)(lds + o);
      long gb = (arow0 + lrow) * 2048 + bn * 512 + lcb;
      *(f32x4*)((char*)Cf32 + gb) = d;
      // fused gumbel + per-tile argmax (same bits as stored logits).
      f32x4 un = *(const f32x4*)((const char*)U + gb);
      float m = -3.4e38f; int mi = 0;
#pragma unroll
      for (int e = 0; e < 4; ++e) {
        float z = d[e];
        if (!test) z += -logf(-logf(un[e] + 1e-20f) + 1e-20f);
        int c = (lcb >> 2) + e;                    // col within 128-tile
        if (z > m) { m = z; mi = c; }              // ascending cols, strict >
      }
      // 32 threads (one half-wave) share row lrow; reduce with min-idx ties.
#pragma unroll
      for (int off = 16; off; off >>= 1) {
        float om = __shfl_xor(m, off);
        int oi = __shfl_xor(mi, off);
        if (om > m || (om == m && oi < mi)) { m = om; mi = oi; }
      }
      if ((tid & 31) == 0) {
        uint2 pr;
        pr.x = __builtin_bit_cast(unsigned, m);
        pr.y = (unsigned)(bn * 128 + mi);
        part[(arow0 + lrow) * 4 + bn] = pr;
      }
    }
  }
}

// ---------------- K3b: partial-argmax reduce + codebook gather ----------------
__global__ void k3b_gather(const uint2* __restrict__ part,
                           const float* __restrict__ cb,
                           float* __restrict__ codes) {
  const int wave = threadIdx.x >> 6, lane = threadIdx.x & 63;
  const long row = (long)blockIdx.x * 4 + wave;    // one wave per row
  // ascending bn with strict > == global first-max (idx ranges disjoint asc.)
  uint2 p0 = part[row * 4 + 0];
  uint2 p1 = part[row * 4 + 1];
  uint2 p2 = part[row * 4 + 2];
  uint2 p3 = part[row * 4 + 3];
  float best = __builtin_bit_cast(float, p0.x);
  int bi = (int)p0.y;
  float v = __builtin_bit_cast(float, p1.x);
  if (v > best) { best = v; bi = (int)p1.y; }
  v = __builtin_bit_cast(float, p2.x);
  if (v > best) { best = v; bi = (int)p2.y; }
  v = __builtin_bit_cast(float, p3.x);
  if (v > best) { best = v; bi = (int)p3.y; }

  const f32x4* src = (const f32x4*)(cb + (long)bi * 512);
  f32x4* dst = (f32x4*)(codes + row * 512);
  dst[lane] = src[lane];
  dst[lane + 64] = src[lane + 64];
}

// ---------------- host ----------------
extern "C" void kernel_launch(void* const* d_in, const int* in_sizes, int n_in,
                              void* d_out, int out_size, void* d_ws, size_t ws_size,
                              hipStream_t stream) {
  const float* X = (const float*)d_in[0];
  const float* Wh = (const float*)d_in[1];
  const float* bh = (const float*)d_in[2];
  const float* Wl = (const float*)d_in[3];
  const float* bl = (const float*)d_in[4];
  const float* cb = (const float*)d_in[5];
  const float* u = (const float*)d_in[6];
  const int* testing = (const int*)d_in[7];

  float* logits = (float*)d_out;                   // 33554432 f32
  float* codes = logits + 33554432;                // 33554432 f32
  // hiddens hi/lo f16 planes live in the codes region until K3b overwrites it
  h16* Hhi = (h16*)codes;
  h16* Hlo = Hhi + 33554432;

  h16* WhHi = (h16*)d_ws;                          // 4 x 0.5 MB weight planes
  h16* WhLo = WhHi + 262144;
  h16* WlHi = WhLo + 262144;
  h16* WlLo = WlHi + 262144;
  uint2* part = (uint2*)((char*)d_ws + 2097152);   // 2 MB argmax partials
  h16* Xhi = (h16*)((char*)d_ws + 4194304);        // 134 MB X planes
  h16* Xlo = Xhi + 33554432;
  const bool presplit = ws_size >= (size_t)4194304 + (size_t)134217728;

  split_w<<<dim3(1024), dim3(256), 0, stream>>>(Wh, Wl, WhHi, WhLo, WlHi, WlLo);

  if (presplit) {
    split_x<<<dim3(32768), dim3(256), 0, stream>>>((const f32x4*)X, (h16x4*)Xhi, (h16x4*)Xlo);
    gemm4_k<0, 0><<<dim3(2048), dim3(256), 0, stream>>>(
        (const void*)Xhi, (const void*)Xlo, WhHi, WhLo, bh, nullptr, Hhi, Hlo,
        nullptr, nullptr, nullptr);
  } else {
    gemm4_k<1, 0><<<dim3(2048), dim3(256), 0, stream>>>(
        (const void*)X, nullptr, WhHi, WhLo, bh, nullptr, Hhi, Hlo,
        nullptr, nullptr, nullptr);
  }
  gemm4_k<0, 1><<<dim3(2048), dim3(256), 0, stream>>>(
      (const void*)Hhi, (const void*)Hlo, WlHi, WlLo, bl, logits, nullptr, nullptr,
      u, testing, part);

  k3b_gather<<<dim3(16384), dim3(256), 0, stream>>>(part, cb, codes);
}

// Round 7
// 345.401 us; speedup vs baseline: 1.1536x; 1.1536x over previous
//
// VQ layer (gumbel-softmax VQ) fused pipeline for MI355X (gfx950). Round 7.
//
//   K0a split_w : W_h, W_logits (512x512 f32) -> f16 hi/lo planes in ws
//   K0b split_x : X (65536x512 f32) -> f16 hi/lo planes in ws (134 MB)
//   K1  gemm4<0,0>: hiddens = relu(X @ Wh^T + bh) -> f16 hi/lo planes in the
//                   codes half of d_out (free until K3)
//   K2  gemm4<0,1>: logits = hiddens @ Wl^T + bl -> d_out (f32). PURE GEMM.
//   K3  argmax  : z = logits + gumbel(u); codes[row,:] = codebook[argmax z,:]
//                 (standalone, high-occupancy: latency-chain work — logf,
//                 shfl reduces, cold u loads — needs ~8 waves/SIMD TLP.
//                 Round-6 lesson: fusing it into the 2-block/CU GEMM
//                 quadrupled its cost, 50us -> 270us.)
//
// f32-GEMM emulation: a = hi + lo*2^-12 (f16 split, lo scaled by 2^12), using
// 3 MFMAs: hi.hi -> acc_hh ; hi.lo + lo.hi -> acc_mx ; D = acc_hh + acc_mx*2^-12.
//
// GEMM v4 (proven): 128x128 tile, 4 waves (64x64 out/wave, 4x4 of 16x16x32
// f16 MFMA — conflict-free b128 shape), BK=32, double-buffered LDS (2x32KB,
// 2 blocks/CU), counted s_waitcnt vmcnt(8) + raw s_barrier (prefetch stays
// in flight across barriers), XOR-swizzled global_load_lds source (rule 21),
// XCD-chunked block swizzle. Presplit A only (round-5 lesson: consumer-side
// f32 split costs 190us vs 60us presplit).

#include <hip/hip_runtime.h>
#include <hip/hip_fp16.h>

typedef _Float16 h16;
typedef __attribute__((ext_vector_type(8))) _Float16 h16x8;
typedef __attribute__((ext_vector_type(4))) _Float16 h16x4;
typedef __attribute__((ext_vector_type(4))) float f32x4;

#define KDIM 512
#define NDIM 512
#define LO_SCALE 4096.0f
#define LO_INV   0.000244140625f

__device__ __forceinline__ void gload16(const void* g, void* l) {
  __builtin_amdgcn_global_load_lds((const __attribute__((address_space(1))) void*)g,
                                   (__attribute__((address_space(3))) void*)l, 16, 0, 0);
}

#define WAITV(n) asm volatile("s_waitcnt vmcnt(" #n ")" ::: "memory")
#define WAITL0() asm volatile("s_waitcnt lgkmcnt(0)" ::: "memory")

// ---------------- K0a: split weights into f16 hi/lo planes ----------------
__global__ void split_w(const float* __restrict__ Wh, const float* __restrict__ Wl,
                        h16* __restrict__ WhHi, h16* __restrict__ WhLo,
                        h16* __restrict__ WlHi, h16* __restrict__ WlLo) {
  int i = blockIdx.x * 256 + threadIdx.x;          // 262144 elements
  float a = Wh[i];
  h16 h = (h16)a;
  WhHi[i] = h; WhLo[i] = (h16)((a - (float)h) * LO_SCALE);
  a = Wl[i];
  h = (h16)a;
  WlHi[i] = h; WlLo[i] = (h16)((a - (float)h) * LO_SCALE);
}

// ---------------- K0b: split inputs into f16 hi/lo planes ----------------
__global__ void split_x(const f32x4* __restrict__ X, h16x4* __restrict__ XHi,
                        h16x4* __restrict__ XLo) {
  int i = blockIdx.x * 256 + threadIdx.x;          // 8388608 f32x4 groups
  f32x4 a = X[i];
  h16x4 hv, lv;
#pragma unroll
  for (int j = 0; j < 4; ++j) {
    h16 h = (h16)a[j];
    hv[j] = h;
    lv[j] = (h16)((a[j] - (float)h) * LO_SCALE);
  }
  XHi[i] = hv; XLo[i] = lv;
}

// ====== GEMM v4: C[m,n] = sum_k A[m,k]*B[n,k] (+bias, epilogue) ======
// AF32=1: A is f32, staged raw and split in-register (slow; fallback only).
// AF32=0: A is presplit f16 hi/lo planes.
// EPI 0: relu + split -> OHi/OLo planes.  EPI 1: f32 -> Cf32.
// Both epilogues repack through LDS for fully-coalesced 16B/lane stores.
template <int AF32, int EPI>
__launch_bounds__(256, 2)
__global__ void gemm4_k(const void* __restrict__ Aptr, const void* __restrict__ AptrLo,
                        const h16* __restrict__ BHi, const h16* __restrict__ BLo,
                        const float* __restrict__ bias,
                        float* __restrict__ Cf32,
                        h16* __restrict__ OHi, h16* __restrict__ OLo) {
  // LDS: 2 stage buffers x 32KB. Per buffer:
  //   A region [0,16K):  AF32 ? [128 rows][128B f32] : [128 rows][hi64|lo64]
  //   B region [16K,32K): [128 rows][hi64|lo64]
  // 128-B rows, granule-XOR swizzle ^((row&7)<<4) applied on SOURCE (stage)
  // and on ds_read address (involution). Epilogue reuses all 64 KB.
  __shared__ __align__(16) char lds[65536];
  const int tid = threadIdx.x;
  const int wave = tid >> 6, lane = tid & 63;
  // XCD-chunked swizzle: 2048 wgs, 8 XCDs, 256 per XCD (bijective)
  const int wg = (blockIdx.x & 7) * 256 + (blockIdx.x >> 3);
  const int bm = wg >> 2, bn = wg & 3;             // 512 row-tiles x 4 col-tiles
  const int wm = wave >> 1, wn = wave & 1;         // 2x2 wave grid, 64x64/wave
  const long arow0 = (long)bm * 128;
  const int brow0 = bn * 128;
  const int q = lane >> 4, rlo = lane & 15;

  f32x4 acc_hh[4][4] = {};
  f32x4 acc_mx[4][4] = {};

  // Stage K-step kt into buffer at bufoff. LDS dest linear (wave-uniform
  // base; HW adds lane*16); source address carries the lane offset + XOR
  // granule swizzle + plane select. 8 gload16 per lane per stage.
#define STAGE4(bufoff, kt)                                                    \
  {                                                                           \
    _Pragma("unroll")                                                         \
    for (int pass = 0; pass < 4; ++pass) {         /* A region: 16KB */       \
      int p = pass * 4096 + wave * 1024 + lane * 16;                          \
      int row = p >> 7;                                                       \
      int gs = ((p >> 4) & 7) ^ (row & 7);                                    \
      if (AF32) {                                                             \
        long off = (arow0 + row) * 2048 + (kt) * 128 + gs * 16;               \
        gload16((const char*)Aptr + off,                                      \
                lds + (bufoff) + pass * 4096 + wave * 1024);                  \
      } else {                                                                \
        const char* sp = (gs & 4) ? (const char*)AptrLo : (const char*)Aptr;  \
        long off = (arow0 + row) * 1024 + (kt) * 64 + (gs & 3) * 16;          \
        gload16(sp + off, lds + (bufoff) + pass * 4096 + wave * 1024);        \
      }                                                                       \
    }                                                                         \
    _Pragma("unroll")                                                         \
    for (int pass = 0; pass < 4; ++pass) {         /* B region: 16KB */       \
      int p = pass * 4096 + wave * 1024 + lane * 16;                          \
      int row = p >> 7;                                                       \
      int gs = ((p >> 4) & 7) ^ (row & 7);                                    \
      const char* sp = (gs & 4) ? (const char*)BLo : (const char*)BHi;        \
      long off = (long)(brow0 + row) * 1024 + (kt) * 64 + (gs & 3) * 16;      \
      gload16(sp + off, lds + (bufoff) + 16384 + pass * 4096 + wave * 1024);  \
    }                                                                         \
  }

  STAGE4(0, 0);
  STAGE4(32768, 1);

#pragma unroll
  for (int t = 0; t < 16; ++t) {
    // counted wait: stage-t loads (oldest 8) landed; stage-(t+1) in flight
    if (t < 15) { WAITV(8); } else { WAITV(0); }
    __builtin_amdgcn_sched_barrier(0);
    __builtin_amdgcn_s_barrier();                  // all waves' t-loads landed
    __builtin_amdgcn_sched_barrier(0);

    const char* buf = lds + (t & 1) * 32768;
    h16x8 ah[4], al[4], bh[4], bl[4];
#pragma unroll
    for (int i = 0; i < 4; ++i) {
      int row = wm * 64 + i * 16 + rlo;
      int sw = (row & 7) << 4;
      if (AF32) {
        f32x4 u0 = *(const f32x4*)(buf + row * 128 + ((q * 32) ^ sw));
        f32x4 u1 = *(const f32x4*)(buf + row * 128 + ((q * 32 + 16) ^ sw));
#pragma unroll
        for (int e = 0; e < 4; ++e) {
          h16 h = (h16)u0[e];
          ah[i][e] = h; al[i][e] = (h16)((u0[e] - (float)h) * LO_SCALE);
          h16 h2 = (h16)u1[e];
          ah[i][4 + e] = h2; al[i][4 + e] = (h16)((u1[e] - (float)h2) * LO_SCALE);
        }
      } else {
        ah[i] = *(const h16x8*)(buf + row * 128 + ((q * 16) ^ sw));
        al[i] = *(const h16x8*)(buf + row * 128 + ((q * 16 + 64) ^ sw));
      }
      int rb = wn * 64 + i * 16 + rlo;
      int swb = (rb & 7) << 4;
      bh[i] = *(const h16x8*)(buf + 16384 + rb * 128 + ((q * 16) ^ swb));
      bl[i] = *(const h16x8*)(buf + 16384 + rb * 128 + ((q * 16 + 64) ^ swb));
    }
#pragma unroll
    for (int i = 0; i < 4; ++i)
#pragma unroll
      for (int j = 0; j < 4; ++j)
        acc_hh[i][j] = __builtin_amdgcn_mfma_f32_16x16x32_f16(ah[i], bh[j], acc_hh[i][j], 0, 0, 0);
#pragma unroll
    for (int i = 0; i < 4; ++i)
#pragma unroll
      for (int j = 0; j < 4; ++j)
        acc_mx[i][j] = __builtin_amdgcn_mfma_f32_16x16x32_f16(ah[i], bl[j], acc_mx[i][j], 0, 0, 0);
#pragma unroll
    for (int i = 0; i < 4; ++i)
#pragma unroll
      for (int j = 0; j < 4; ++j)
        acc_mx[i][j] = __builtin_amdgcn_mfma_f32_16x16x32_f16(al[i], bh[j], acc_mx[i][j], 0, 0, 0);

    WAITL0();                                      // our reads of buf done
    __builtin_amdgcn_sched_barrier(0);
    __builtin_amdgcn_s_barrier();                  // safe to overwrite buf
    __builtin_amdgcn_sched_barrier(0);
    if (t + 2 < 16) STAGE4((t & 1) * 32768, t + 2);
  }
#undef STAGE4

  // ---- epilogue. C/D layout (16x16, m89): col=lane&15, row=(lane>>4)*4+r.
  // Repack tile through LDS (stage buffers dead), then coalesced stores.
#pragma unroll
  for (int j = 0; j < 4; ++j) {
    int lcol = wn * 64 + j * 16 + rlo;
    float bv = bias[bn * 128 + lcol];
#pragma unroll
    for (int i = 0; i < 4; ++i)
#pragma unroll
      for (int r = 0; r < 4; ++r) {
        int lrow = wm * 64 + i * 16 + q * 4 + r;
        float v = acc_hh[i][j][r] + acc_mx[i][j][r] * LO_INV + bv;
        if (EPI == 0) {
          v = fmaxf(v, 0.0f);
          h16 h = (h16)v;
          h16 l = (h16)((v - (float)h) * LO_SCALE);
          unsigned uu = (unsigned)__builtin_bit_cast(unsigned short, h) |
                        ((unsigned)__builtin_bit_cast(unsigned short, l) << 16);
          *(unsigned*)(lds + lrow * 512 + lcol * 4) = uu;
        } else {
          *(float*)(lds + lrow * 512 + lcol * 4) = v;
        }
      }
  }
  __syncthreads();
#pragma unroll
  for (int pass = 0; pass < 16; ++pass) {
    int o = pass * 4096 + tid * 16;
    int lrow = o >> 9;                             // 512-B packed rows
    int lcb = o & 511;
    if (EPI == 0) {
      uint4 d = *(const uint4*)(lds + o);
      uint2 hi, lo;
      hi.x = (d.x & 0xffffu) | (d.y << 16);
      hi.y = (d.z & 0xffffu) | (d.w << 16);
      lo.x = (d.x >> 16) | (d.y & 0xffff0000u);
      lo.y = (d.z >> 16) | (d.w & 0xffff0000u);
      long gb = (arow0 + lrow) * 1024 + bn * 256 + (lcb >> 1);
      *(uint2*)((char*)OHi + gb) = hi;
      *(uint2*)((char*)OLo + gb) = lo;
    } else {
      f32x4 d = *(const f32x4*)(lds + o);
      long gb = (arow0 + lrow) * 2048 + bn * 512 + lcb;
      *(f32x4*)((char*)Cf32 + gb) = d;
    }
  }
}

// ---------------- K3: gumbel + argmax + codebook gather ----------------
// Standalone, high-occupancy (small kernel, ~8 waves/SIMD): the logf chains,
// shfl reduces and cold u loads are latency-bound and need TLP to hide.
__global__ void k3_argmax_gather(const float* __restrict__ logits,
                                 const float* __restrict__ u,
                                 const float* __restrict__ cb,
                                 const int* __restrict__ testing,
                                 float* __restrict__ codes) {
  const int wave = threadIdx.x >> 6, lane = threadIdx.x & 63;
  const long row = (long)blockIdx.x * 4 + wave;    // one wave per row
  const f32x4* lrow = (const f32x4*)(logits + row * 512);
  const f32x4* urow = (const f32x4*)(u + row * 512);
  const int test = *testing;

  float best = -3.4e38f;
  int bi = 0;
#pragma unroll
  for (int h = 0; h < 2; ++h) {
    int c4 = h * 64 + lane;
    f32x4 z = lrow[c4];
    if (!test) {
      f32x4 uu = urow[c4];
#pragma unroll
      for (int t = 0; t < 4; ++t)
        z[t] += -logf(-logf(uu[t] + 1e-20f) + 1e-20f);
    }
#pragma unroll
    for (int t = 0; t < 4; ++t) {                  // in-lane ascending indices
      int c = c4 * 4 + t;
      if (z[t] > best) { best = z[t]; bi = c; }
    }
  }
#pragma unroll
  for (int off = 32; off; off >>= 1) {             // max with min-index ties
    float ob = __shfl_xor(best, off);
    int oi = __shfl_xor(bi, off);
    if (ob > best || (ob == best && oi < bi)) { best = ob; bi = oi; }
  }
  const f32x4* src = (const f32x4*)(cb + (long)bi * 512);
  f32x4* dst = (f32x4*)(codes + row * 512);
  dst[lane] = src[lane];
  dst[lane + 64] = src[lane + 64];
}

// ---------------- host ----------------
extern "C" void kernel_launch(void* const* d_in, const int* in_sizes, int n_in,
                              void* d_out, int out_size, void* d_ws, size_t ws_size,
                              hipStream_t stream) {
  const float* X = (const float*)d_in[0];
  const float* Wh = (const float*)d_in[1];
  const float* bh = (const float*)d_in[2];
  const float* Wl = (const float*)d_in[3];
  const float* bl = (const float*)d_in[4];
  const float* cb = (const float*)d_in[5];
  const float* u = (const float*)d_in[6];
  const int* testing = (const int*)d_in[7];

  float* logits = (float*)d_out;                   // 33554432 f32
  float* codes = logits + 33554432;                // 33554432 f32
  // hiddens hi/lo f16 planes live in the codes region until K3 overwrites it
  h16* Hhi = (h16*)codes;
  h16* Hlo = Hhi + 33554432;

  h16* WhHi = (h16*)d_ws;                          // 4 x 0.5 MB weight planes
  h16* WhLo = WhHi + 262144;
  h16* WlHi = WhLo + 262144;
  h16* WlLo = WlHi + 262144;
  h16* Xhi = (h16*)((char*)d_ws + 2097152);        // 134 MB X planes
  h16* Xlo = Xhi + 33554432;
  const bool presplit = ws_size >= (size_t)2097152 + (size_t)134217728;

  split_w<<<dim3(1024), dim3(256), 0, stream>>>(Wh, Wl, WhHi, WhLo, WlHi, WlLo);

  if (presplit) {
    split_x<<<dim3(32768), dim3(256), 0, stream>>>((const f32x4*)X, (h16x4*)Xhi, (h16x4*)Xlo);
    gemm4_k<0, 0><<<dim3(2048), dim3(256), 0, stream>>>(
        (const void*)Xhi, (const void*)Xlo, WhHi, WhLo, bh, nullptr, Hhi, Hlo);
  } else {
    gemm4_k<1, 0><<<dim3(2048), dim3(256), 0, stream>>>(
        (const void*)X, nullptr, WhHi, WhLo, bh, nullptr, Hhi, Hlo);
  }
  gemm4_k<0, 1><<<dim3(2048), dim3(256), 0, stream>>>(
      (const void*)Hhi, (const void*)Hlo, WlHi, WlLo, bl, logits, nullptr, nullptr);

  k3_argmax_gather<<<dim3(16384), dim3(256), 0, stream>>>(logits, u, cb, testing, codes);
}

// Round 10
// 298.517 us; speedup vs baseline: 1.3347x; 1.1571x over previous
//
// VQ layer (gumbel-softmax VQ) fused pipeline for MI355X (gfx950). Round 8 resubmit (2).
//
//   K0  split_w : W_h, W_logits (512x512 f32) -> f16 hi/lo planes in ws (2 MB)
//   K1  gemm5   : hiddens = relu(X @ Wh^T + bh); A staged global->reg->LDS
//                 with PRODUCER-side f32->f16 hi/lo split (T14 async-STAGE,
//                 one-iteration load lookahead); output -> f16 hi/lo planes
//                 in the codes half of d_out (free until K3)
//   K2  gemm4<0,1>: logits = hiddens @ Wl^T + bl -> d_out (f32). PURE GEMM.
//   K3  argmax  : z = logits + gumbel(u); codes[row,:] = codebook[argmax z,:]
//                 (standalone high-occupancy; round-6 lesson: latency-chain
//                 work fused into a 2-block/CU GEMM quadruples its cost)
//
// Round-7 lesson (R5 vs R7 controlled A/B): materializing X hi/lo planes
// (split_x) is a net LOSS — a 402 MB pass plus 134 MB of dirty L3 that gets
// written back under later kernels. Round-5 lesson: consumer-side split (after
// ds_read, before MFMA) is also a loss (190us vs ~60us K-loop). This round:
// producer-side reg split — the split VALU sits in the stage zone, one
// iteration ahead of consumption, off the MFMA critical path.
//
// f32-GEMM emulation: a = hi + lo*2^-12 (f16 split, lo scaled by 2^12), using
// 3 MFMAs: hi.hi -> acc_hh ; hi.lo + lo.hi -> acc_mx ; D = acc_hh + acc_mx*2^-12.
//
// GEMM shell (proven R5/R7): 128x128 tile, 4 waves, 4x4 of 16x16x32 f16 MFMA
// (conflict-free b128 shape), BK=32, double-buffered LDS (2x32KB, 2 blocks/CU),
// counted vmcnt + raw s_barrier (loads stay in flight across barriers),
// XOR-swizzled LDS (rule 21: same involution on write addr and read addr),
// XCD-chunked block swizzle (2048%8==0).

#include <hip/hip_runtime.h>
#include <hip/hip_fp16.h>

typedef _Float16 h16;
typedef __attribute__((ext_vector_type(8))) _Float16 h16x8;
typedef __attribute__((ext_vector_type(4))) _Float16 h16x4;
typedef __attribute__((ext_vector_type(4))) float f32x4;

#define KDIM 512
#define NDIM 512
#define LO_SCALE 4096.0f
#define LO_INV   0.000244140625f

__device__ __forceinline__ void gload16(const void* g, void* l) {
  __builtin_amdgcn_global_load_lds((const __attribute__((address_space(1))) void*)g,
                                   (__attribute__((address_space(3))) void*)l, 16, 0, 0);
}

#define WAITV(n) asm volatile("s_waitcnt vmcnt(" #n ")" ::: "memory")
#define WAITL0() asm volatile("s_waitcnt lgkmcnt(0)" ::: "memory")
#define SB() __builtin_amdgcn_sched_barrier(0)

// ---------------- K0: split weights into f16 hi/lo planes ----------------
__global__ void split_w(const float* __restrict__ Wh, const float* __restrict__ Wl,
                        h16* __restrict__ WhHi, h16* __restrict__ WhLo,
                        h16* __restrict__ WlHi, h16* __restrict__ WlLo) {
  int i = blockIdx.x * 256 + threadIdx.x;          // 262144 elements
  float a = Wh[i];
  h16 h = (h16)a;
  WhHi[i] = h; WhLo[i] = (h16)((a - (float)h) * LO_SCALE);
  a = Wl[i];
  h = (h16)a;
  WlHi[i] = h; WlLo[i] = (h16)((a - (float)h) * LO_SCALE);
}

// ====== K1: gemm5 — C = relu(X @ Wh^T + bh), producer-split A ======
__launch_bounds__(256, 2)
__global__ void gemm5_k(const float* __restrict__ X,
                        const h16* __restrict__ BHi, const h16* __restrict__ BLo,
                        const float* __restrict__ bias,
                        h16* __restrict__ OHi, h16* __restrict__ OLo) {
  // LDS: 2 stage buffers x 32KB: A [0,16K) = [128 rows][hi64|lo64],
  // B [16K,32K) = [128 rows][hi64|lo64]. 128-B rows, granule XOR swizzle
  // ^((row&7)<<4) on both write addr (A: ds_write; B: pre-swizzled source)
  // and read addr. Epilogue reuses all 64 KB for the repack.
  __shared__ __align__(16) char lds[65536];
  const int tid = threadIdx.x;
  const int wave = tid >> 6, lane = tid & 63;
  const int wg = (blockIdx.x & 7) * 256 + (blockIdx.x >> 3);
  const int bm = wg >> 2, bn = wg & 3;
  const int wm = wave >> 1, wn = wave & 1;
  const long arow0 = (long)bm * 128;
  const int brow0 = bn * 128;
  const int q = lane >> 4, rlo = lane & 15;

  f32x4 acc_hh[4][4] = {};
  f32x4 acc_mx[4][4] = {};
  f32x4 areg[2][4];                                // 2 in-flight A k-steps

  // A-step load: 4x dwordx4, wave-contiguous (lane-linear 16B) -> coalesced.
  auto aload = [&](f32x4 (&ar)[4], int kt) {
#pragma unroll
    for (int i = 0; i < 4; ++i) {
      int so = i * 4096 + tid * 16;                // slab [128 rows][128B]
      int r = so >> 7, cbyte = so & 127;
      ar[i] = *(const f32x4*)((const char*)X + (arow0 + r) * 2048 + (long)kt * 128 + cbyte);
    }
  };
  // A-step split + ds_write into buffer (same layout the consumer reads).
  auto awrite = [&](f32x4 (&ar)[4], int bufoff) {
#pragma unroll
    for (int i = 0; i < 4; ++i) {
      int so = i * 4096 + tid * 16;
      int r = so >> 7;
      int jb = (tid & 7) * 8;                      // hi-plane byte within row
      int sw = (r & 7) << 4;
      f32x4 a = ar[i];
      h16x4 hv, lv;
#pragma unroll
      for (int e = 0; e < 4; ++e) {
        h16 h = (h16)a[e];
        hv[e] = h;
        lv[e] = (h16)((a[e] - (float)h) * LO_SCALE);
      }
      *(h16x4*)(lds + bufoff + r * 128 + (jb ^ sw)) = hv;
      *(h16x4*)(lds + bufoff + r * 128 + ((jb + 64) ^ sw)) = lv;
    }
  };
  // B staging: 4x global_load_lds from presplit weight planes.
  auto bgld = [&](int bufoff, int kt) {
#pragma unroll
    for (int pass = 0; pass < 4; ++pass) {
      int p = pass * 4096 + wave * 1024 + lane * 16;
      int row = p >> 7;
      int gs = ((p >> 4) & 7) ^ (row & 7);
      const char* sp = (gs & 4) ? (const char*)BLo : (const char*)BHi;
      long off = (long)(brow0 + row) * 1024 + (long)kt * 64 + (gs & 3) * 16;
      gload16(sp + off, lds + bufoff + 16384 + pass * 4096 + wave * 1024);
    }
  };

  // ---- prologue: steps 0,1 staged; step-2 A loads in flight ----
  aload(areg[0], 0);
  aload(areg[1], 1);
  WAITV(4);                                        // areg[0] landed
  awrite(areg[0], 0);
  bgld(0, 0);
  WAITV(4);                                        // areg[1] landed (B0 flies)
  awrite(areg[1], 32768);
  aload(areg[0], 2);                               // outstanding: B0, A2
  bgld(32768, 1);                                  // outstanding: B0, A2, B1
  WAITL0();                                        // ds_writes visible pre-bar

#pragma unroll
  for (int t = 0; t < 16; ++t) {
    // pre-barrier: wait this step's B (oldest); later loads stay in flight
    if (t <= 13) { WAITV(8); } else if (t == 14) { WAITV(4); } else { WAITV(0); }
    SB();
    __builtin_amdgcn_s_barrier();                  // buf[t&1] fully staged
    SB();

    const char* buf = lds + (t & 1) * 32768;
    h16x8 ah[4], al[4], bh[4], bl[4];
#pragma unroll
    for (int i = 0; i < 4; ++i) {
      int row = wm * 64 + i * 16 + rlo;
      int sw = (row & 7) << 4;
      ah[i] = *(const h16x8*)(buf + row * 128 + ((q * 16) ^ sw));
      al[i] = *(const h16x8*)(buf + row * 128 + ((q * 16 + 64) ^ sw));
      int rb = wn * 64 + i * 16 + rlo;
      int swb = (rb & 7) << 4;
      bh[i] = *(const h16x8*)(buf + 16384 + rb * 128 + ((q * 16) ^ swb));
      bl[i] = *(const h16x8*)(buf + 16384 + rb * 128 + ((q * 16 + 64) ^ swb));
    }
#pragma unroll
    for (int i = 0; i < 4; ++i)
#pragma unroll
      for (int j = 0; j < 4; ++j)
        acc_hh[i][j] = __builtin_amdgcn_mfma_f32_16x16x32_f16(ah[i], bh[j], acc_hh[i][j], 0, 0, 0);
#pragma unroll
    for (int i = 0; i < 4; ++i)
#pragma unroll
      for (int j = 0; j < 4; ++j)
        acc_mx[i][j] = __builtin_amdgcn_mfma_f32_16x16x32_f16(ah[i], bl[j], acc_mx[i][j], 0, 0, 0);
#pragma unroll
    for (int i = 0; i < 4; ++i)
#pragma unroll
      for (int j = 0; j < 4; ++j)
        acc_mx[i][j] = __builtin_amdgcn_mfma_f32_16x16x32_f16(al[i], bh[j], acc_mx[i][j], 0, 0, 0);

    WAITL0();                                      // our ds_reads of buf done
    SB();
    __builtin_amdgcn_s_barrier();                  // all waves done with buf
    SB();
    // ---- stage zone: buf[t&1] now free; stage step t+2 into it ----
    if (t <= 12) {
      aload(areg[(t + 3) & 1], t + 3);             // issue next-next A loads
      WAITV(8);                                    // A(t+2) landed (oldest)
      awrite(areg[(t + 2) & 1], (t & 1) * 32768);
      bgld((t & 1) * 32768, t + 2);
    } else if (t == 13) {
      WAITV(4);                                    // A(15) landed (B14 flies)
      awrite(areg[1], 32768);
      bgld(32768, 15);
    }
  }

  // ---- epilogue: relu + split -> planes, repacked via LDS, coalesced ----
#pragma unroll
  for (int j = 0; j < 4; ++j) {
    int lcol = wn * 64 + j * 16 + rlo;
    float bv = bias[bn * 128 + lcol];
#pragma unroll
    for (int i = 0; i < 4; ++i)
#pragma unroll
      for (int r = 0; r < 4; ++r) {
        int lrow = wm * 64 + i * 16 + q * 4 + r;
        float v = fmaxf(acc_hh[i][j][r] + acc_mx[i][j][r] * LO_INV + bv, 0.0f);
        h16 h = (h16)v;
        h16 l = (h16)((v - (float)h) * LO_SCALE);
        unsigned uu = (unsigned)__builtin_bit_cast(unsigned short, h) |
                      ((unsigned)__builtin_bit_cast(unsigned short, l) << 16);
        *(unsigned*)(lds + lrow * 512 + lcol * 4) = uu;
      }
  }
  __syncthreads();
#pragma unroll
  for (int pass = 0; pass < 16; ++pass) {
    int o = pass * 4096 + tid * 16;
    int lrow = o >> 9;
    int lcb = o & 511;
    uint4 d = *(const uint4*)(lds + o);
    uint2 hi, lo;
    hi.x = (d.x & 0xffffu) | (d.y << 16);
    hi.y = (d.z & 0xffffu) | (d.w << 16);
    lo.x = (d.x >> 16) | (d.y & 0xffff0000u);
    lo.y = (d.z >> 16) | (d.w & 0xffff0000u);
    long gb = (arow0 + lrow) * 1024 + bn * 256 + (lcb >> 1);
    *(uint2*)((char*)OHi + gb) = hi;
    *(uint2*)((char*)OLo + gb) = lo;
  }
}

// ====== K2: gemm4 (presplit A planes) — logits, pure GEMM (proven) ======
template <int AF32, int EPI>
__launch_bounds__(256, 2)
__global__ void gemm4_k(const void* __restrict__ Aptr, const void* __restrict__ AptrLo,
                        const h16* __restrict__ BHi, const h16* __restrict__ BLo,
                        const float* __restrict__ bias,
                        float* __restrict__ Cf32,
                        h16* __restrict__ OHi, h16* __restrict__ OLo) {
  __shared__ __align__(16) char lds[65536];
  const int tid = threadIdx.x;
  const int wave = tid >> 6, lane = tid & 63;
  const int wg = (blockIdx.x & 7) * 256 + (blockIdx.x >> 3);
  const int bm = wg >> 2, bn = wg & 3;
  const int wm = wave >> 1, wn = wave & 1;
  const long arow0 = (long)bm * 128;
  const int brow0 = bn * 128;
  const int q = lane >> 4, rlo = lane & 15;

  f32x4 acc_hh[4][4] = {};
  f32x4 acc_mx[4][4] = {};

#define STAGE4(bufoff, kt)                                                    \
  {                                                                           \
    _Pragma("unroll")                                                         \
    for (int pass = 0; pass < 4; ++pass) {                                    \
      int p = pass * 4096 + wave * 1024 + lane * 16;                          \
      int row = p >> 7;                                                       \
      int gs = ((p >> 4) & 7) ^ (row & 7);                                    \
      const char* sp = (gs & 4) ? (const char*)AptrLo : (const char*)Aptr;    \
      long off = (arow0 + row) * 1024 + (kt) * 64 + (gs & 3) * 16;            \
      gload16(sp + off, lds + (bufoff) + pass * 4096 + wave * 1024);          \
    }                                                                         \
    _Pragma("unroll")                                                         \
    for (int pass = 0; pass < 4; ++pass) {                                    \
      int p = pass * 4096 + wave * 1024 + lane * 16;                          \
      int row = p >> 7;                                                       \
      int gs = ((p >> 4) & 7) ^ (row & 7);                                    \
      const char* sp = (gs & 4) ? (const char*)BLo : (const char*)BHi;        \
      long off = (long)(brow0 + row) * 1024 + (kt) * 64 + (gs & 3) * 16;      \
      gload16(sp + off, lds + (bufoff) + 16384 + pass * 4096 + wave * 1024);  \
    }                                                                         \
  }

  STAGE4(0, 0);
  STAGE4(32768, 1);

#pragma unroll
  for (int t = 0; t < 16; ++t) {
    if (t < 15) { WAITV(8); } else { WAITV(0); }
    SB();
    __builtin_amdgcn_s_barrier();
    SB();

    const char* buf = lds + (t & 1) * 32768;
    h16x8 ah[4], al[4], bh[4], bl[4];
#pragma unroll
    for (int i = 0; i < 4; ++i) {
      int row = wm * 64 + i * 16 + rlo;
      int sw = (row & 7) << 4;
      ah[i] = *(const h16x8*)(buf + row * 128 + ((q * 16) ^ sw));
      al[i] = *(const h16x8*)(buf + row * 128 + ((q * 16 + 64) ^ sw));
      int rb = wn * 64 + i * 16 + rlo;
      int swb = (rb & 7) << 4;
      bh[i] = *(const h16x8*)(buf + 16384 + rb * 128 + ((q * 16) ^ swb));
      bl[i] = *(const h16x8*)(buf + 16384 + rb * 128 + ((q * 16 + 64) ^ swb));
    }
#pragma unroll
    for (int i = 0; i < 4; ++i)
#pragma unroll
      for (int j = 0; j < 4; ++j)
        acc_hh[i][j] = __builtin_amdgcn_mfma_f32_16x16x32_f16(ah[i], bh[j], acc_hh[i][j], 0, 0, 0);
#pragma unroll
    for (int i = 0; i < 4; ++i)
#pragma unroll
      for (int j = 0; j < 4; ++j)
        acc_mx[i][j] = __builtin_amdgcn_mfma_f32_16x16x32_f16(ah[i], bl[j], acc_mx[i][j], 0, 0, 0);
#pragma unroll
    for (int i = 0; i < 4; ++i)
#pragma unroll
      for (int j = 0; j < 4; ++j)
        acc_mx[i][j] = __builtin_amdgcn_mfma_f32_16x16x32_f16(al[i], bh[j], acc_mx[i][j], 0, 0, 0);

    WAITL0();
    SB();
    __builtin_amdgcn_s_barrier();
    SB();
    if (t + 2 < 16) STAGE4((t & 1) * 32768, t + 2);
  }
#undef STAGE4

#pragma unroll
  for (int j = 0; j < 4; ++j) {
    int lcol = wn * 64 + j * 16 + rlo;
    float bv = bias[bn * 128 + lcol];
#pragma unroll
    for (int i = 0; i < 4; ++i)
#pragma unroll
      for (int r = 0; r < 4; ++r) {
        int lrow = wm * 64 + i * 16 + q * 4 + r;
        float v = acc_hh[i][j][r] + acc_mx[i][j][r] * LO_INV + bv;
        if (EPI == 0) {
          v = fmaxf(v, 0.0f);
          h16 h = (h16)v;
          h16 l = (h16)((v - (float)h) * LO_SCALE);
          unsigned uu = (unsigned)__builtin_bit_cast(unsigned short, h) |
                        ((unsigned)__builtin_bit_cast(unsigned short, l) << 16);
          *(unsigned*)(lds + lrow * 512 + lcol * 4) = uu;
        } else {
          *(float*)(lds + lrow * 512 + lcol * 4) = v;
        }
      }
  }
  __syncthreads();
#pragma unroll
  for (int pass = 0; pass < 16; ++pass) {
    int o = pass * 4096 + tid * 16;
    int lrow = o >> 9;
    int lcb = o & 511;
    if (EPI == 0) {
      uint4 d = *(const uint4*)(lds + o);
      uint2 hi, lo;
      hi.x = (d.x & 0xffffu) | (d.y << 16);
      hi.y = (d.z & 0xffffu) | (d.w << 16);
      lo.x = (d.x >> 16) | (d.y & 0xffff0000u);
      lo.y = (d.z >> 16) | (d.w & 0xffff0000u);
      long gb = (arow0 + lrow) * 1024 + bn * 256 + (lcb >> 1);
      *(uint2*)((char*)OHi + gb) = hi;
      *(uint2*)((char*)OLo + gb) = lo;
    } else {
      f32x4 d = *(const f32x4*)(lds + o);
      long gb = (arow0 + lrow) * 2048 + bn * 512 + lcb;
      *(f32x4*)((char*)Cf32 + gb) = d;
    }
  }
}

// ---------------- K3: gumbel + argmax + codebook gather ----------------
__global__ void k3_argmax_gather(const float* __restrict__ logits,
                                 const float* __restrict__ u,
                                 const float* __restrict__ cb,
                                 const int* __restrict__ testing,
                                 float* __restrict__ codes) {
  const int wave = threadIdx.x >> 6, lane = threadIdx.x & 63;
  const long row = (long)blockIdx.x * 4 + wave;    // one wave per row
  const f32x4* lrow = (const f32x4*)(logits + row * 512);
  const f32x4* urow = (const f32x4*)(u + row * 512);
  const int test = *testing;

  float best = -3.4e38f;
  int bi = 0;
#pragma unroll
  for (int h = 0; h < 2; ++h) {
    int c4 = h * 64 + lane;
    f32x4 z = lrow[c4];
    if (!test) {
      f32x4 uu = urow[c4];
#pragma unroll
      for (int t = 0; t < 4; ++t)
        z[t] += -logf(-logf(uu[t] + 1e-20f) + 1e-20f);
    }
#pragma unroll
    for (int t = 0; t < 4; ++t) {                  // in-lane ascending indices
      int c = c4 * 4 + t;
      if (z[t] > best) { best = z[t]; bi = c; }
    }
  }
#pragma unroll
  for (int off = 32; off; off >>= 1) {             // max with min-index ties
    float ob = __shfl_xor(best, off);
    int oi = __shfl_xor(bi, off);
    if (ob > best || (ob == best && oi < bi)) { best = ob; bi = oi; }
  }
  const f32x4* src = (const f32x4*)(cb + (long)bi * 512);
  f32x4* dst = (f32x4*)(codes + row * 512);
  dst[lane] = src[lane];
  dst[lane + 64] = src[lane + 64];
}

// ---------------- host ----------------
extern "C" void kernel_launch(void* const* d_in, const int* in_sizes, int n_in,
                              void* d_out, int out_size, void* d_ws, size_t ws_size,
                              hipStream_t stream) {
  const float* X = (const float*)d_in[0];
  const float* Wh = (const float*)d_in[1];
  const float* bh = (const float*)d_in[2];
  const float* Wl = (const float*)d_in[3];
  const float* bl = (const float*)d_in[4];
  const float* cb = (const float*)d_in[5];
  const float* u = (const float*)d_in[6];
  const int* testing = (const int*)d_in[7];

  float* logits = (float*)d_out;                   // 33554432 f32
  float* codes = logits + 33554432;                // 33554432 f32
  // hiddens hi/lo f16 planes live in the codes region until K3 overwrites it
  h16* Hhi = (h16*)codes;
  h16* Hlo = Hhi + 33554432;

  h16* WhHi = (h16*)d_ws;                          // 4 x 0.5 MB weight planes
  h16* WhLo = WhHi + 262144;
  h16* WlHi = WhLo + 262144;
  h16* WlLo = WlHi + 262144;

  split_w<<<dim3(1024), dim3(256), 0, stream>>>(Wh, Wl, WhHi, WhLo, WlHi, WlLo);

  gemm5_k<<<dim3(2048), dim3(256), 0, stream>>>(X, WhHi, WhLo, bh, Hhi, Hlo);

  gemm4_k<0, 1><<<dim3(2048), dim3(256), 0, stream>>>(
      (const void*)Hhi, (const void*)Hlo, WlHi, WlLo, bl, logits, nullptr, nullptr);

  k3_argmax_gather<<<dim3(16384), dim3(256), 0, stream>>>(logits, u, cb, testing, codes);
}